// Round 1
// baseline (246.002 us; speedup 1.0000x reference)
//
#include <hip/hip_runtime.h>

// VectorQuantization: x (32,64,64,64) f32, embedding (512,64) f32
// out = [quantized_ste (8388608 f32)] ++ [loss (1 f32)]

#define C_DIM 64
#define K_EMB 512
#define NVEC_TOTAL (32 * 64 * 64)          // 131072
#define MAIN_BLOCK 512
#define MAIN_GRID (NVEC_TOTAL / MAIN_BLOCK) // 256

// ws layout:
//   [0, 2048)            float e2[512]
//   [2048, 2048+256*8)   double partials[256]

__global__ __launch_bounds__(K_EMB) void vq_prep(const float* __restrict__ emb,
                                                 float* __restrict__ e2) {
    const int k = threadIdx.x; // 512 threads, one per embedding
    const float4* ev = (const float4*)(emb + k * C_DIM);
    float s = 0.f;
#pragma unroll
    for (int i = 0; i < C_DIM / 4; ++i) {
        float4 v = ev[i];
        s += v.x * v.x + v.y * v.y + v.z * v.z + v.w * v.w;
    }
    e2[k] = s;
}

__global__ __launch_bounds__(MAIN_BLOCK) void vq_main(
    const float* __restrict__ x,
    const float* __restrict__ emb,
    const float* __restrict__ e2,
    float* __restrict__ out,
    double* __restrict__ partials)
{
    const int n = blockIdx.x * MAIN_BLOCK + threadIdx.x;

    // ---- load this thread's vector into registers (fully unrolled) ----
    float xr[C_DIM];
    float x2 = 0.f;
    {
        const float4* xv = (const float4*)(x + (size_t)n * C_DIM);
#pragma unroll
        for (int i = 0; i < C_DIM / 4; ++i) {
            float4 v = xv[i];
            xr[4 * i + 0] = v.x; xr[4 * i + 1] = v.y;
            xr[4 * i + 2] = v.z; xr[4 * i + 3] = v.w;
            x2 += v.x * v.x + v.y * v.y + v.z * v.z + v.w * v.w;
        }
    }

    // ---- argmin over K embeddings, tracking top-2 ----
    // score_k = e2[k] - 2*dot(x, e_k)   (x2 omitted: constant per vector)
    float best1 = 3.4e38f, best2 = 3.4e38f;
    int   bi1 = 0, bi2 = 0;

    for (int k = 0; k < K_EMB; ++k) {
        // k is wave-uniform -> these loads should compile to s_load (scalar pipe)
        const float4* ev4 = (const float4*)(emb + k * C_DIM);
        float d0 = 0.f, d1 = 0.f, d2 = 0.f, d3 = 0.f;
#pragma unroll
        for (int i = 0; i < C_DIM / 4; ++i) {
            float4 e = ev4[i];
            d0 = fmaf(xr[4 * i + 0], e.x, d0);
            d1 = fmaf(xr[4 * i + 1], e.y, d1);
            d2 = fmaf(xr[4 * i + 2], e.z, d2);
            d3 = fmaf(xr[4 * i + 3], e.w, d3);
        }
        float dot = (d0 + d1) + (d2 + d3);
        float score = e2[k] - 2.0f * dot;

        bool b1 = score < best1;
        bool b2 = score < best2;
        best2 = b1 ? best1 : (b2 ? score : best2);
        bi2   = b1 ? bi1   : (b2 ? k     : bi2);
        best1 = b1 ? score : best1;
        bi1   = b1 ? k     : bi1;
    }

    float md = x2 + best1; // squared distance of winner (fp32)

    // ---- near-tie refinement in fp64 (rare path) ----
    if (best2 - best1 < 1e-2f) {
        const float* p1 = emb + bi1 * C_DIM;
        const float* p2 = emb + bi2 * C_DIM;
        double s1 = 0.0, s2 = 0.0;
#pragma unroll
        for (int c = 0; c < C_DIM; ++c) {
            double a = (double)xr[c] - (double)p1[c];
            double b = (double)xr[c] - (double)p2[c];
            s1 = fma(a, a, s1);
            s2 = fma(b, b, s2);
        }
        if (s2 < s1 || (s1 == s2 && bi2 < bi1)) {
            bi1 = bi2;
            md = (float)s2;
        } else {
            md = (float)s1;
        }
    }

    // ---- write quantized vector (== quantized_ste numerically) ----
    {
        const float4* qe = (const float4*)(emb + bi1 * C_DIM);
        float4* op = (float4*)(out + (size_t)n * C_DIM);
#pragma unroll
        for (int i = 0; i < C_DIM / 4; ++i) op[i] = qe[i];
    }

    // ---- deterministic loss partial: block reduction of md ----
    double v = (double)md;
#pragma unroll
    for (int off = 32; off; off >>= 1) v += __shfl_down(v, off, 64);
    __shared__ double ls[MAIN_BLOCK / 64];
    const int lane = threadIdx.x & 63;
    const int wid  = threadIdx.x >> 6;
    if (lane == 0) ls[wid] = v;
    __syncthreads();
    if (threadIdx.x == 0) {
        double t = 0.0;
#pragma unroll
        for (int i = 0; i < MAIN_BLOCK / 64; ++i) t += ls[i];
        partials[blockIdx.x] = t;
    }
}

__global__ __launch_bounds__(256) void vq_finalize(const double* __restrict__ partials,
                                                   float* __restrict__ out) {
    // 256 threads, one per block partial
    double v = partials[threadIdx.x];
#pragma unroll
    for (int off = 32; off; off >>= 1) v += __shfl_down(v, off, 64);
    __shared__ double ls[4];
    const int lane = threadIdx.x & 63;
    const int wid  = threadIdx.x >> 6;
    if (lane == 0) ls[wid] = v;
    __syncthreads();
    if (threadIdx.x == 0) {
        double t = ls[0] + ls[1] + ls[2] + ls[3];
        double mean = t / (double)((size_t)NVEC_TOTAL * C_DIM);
        // loss = embedding_loss + 0.25*encoding_loss = 1.25 * mean((x-q)^2)
        out[(size_t)NVEC_TOTAL * C_DIM] = (float)(1.25 * mean);
    }
}

extern "C" void kernel_launch(void* const* d_in, const int* in_sizes, int n_in,
                              void* d_out, int out_size, void* d_ws, size_t ws_size,
                              hipStream_t stream) {
    const float* x   = (const float*)d_in[0];
    const float* emb = (const float*)d_in[1];
    float* out = (float*)d_out;

    float*  e2       = (float*)d_ws;
    double* partials = (double*)((char*)d_ws + 2048);

    vq_prep<<<1, K_EMB, 0, stream>>>(emb, e2);
    vq_main<<<MAIN_GRID, MAIN_BLOCK, 0, stream>>>(x, emb, e2, out, partials);
    vq_finalize<<<1, 256, 0, stream>>>(partials, out);
}

// Round 2
// 67.680 us; speedup vs baseline: 3.6348x; 3.6348x over previous
//
#include <hip/hip_runtime.h>

// VectorQuantization: x (32,64,64,64) f32, embedding (512,64) f32
// out = [quantized_ste (8388608 f32)] ++ [loss (1 f32)]
//
// MFMA formulation: score[k,n] = e2[k] - 2*dot(e_k, x_n)  (x2 added later)
// A = bf16 split of (-2*emb) (M=16 k-rows, K=32 c), B = bf16 split of x
// (K=32 c, N=16 vectors), D = 16k x 16n, f32.
// 3-pass split: Ahi*Bhi + Alo*Bhi + Ahi*Blo  (lo*lo dropped, err ~1e-3 worst)
// top-2 + fp64 refine at gap<1e-2 resolves ties (same scheme as passing r1).

#define C_DIM 64
#define K_EMB 512
#define NVEC (32 * 64 * 64)     // 131072
#define BLK 512                 // 8 waves
#define NPB 256                 // vectors per block (8 waves x 32)
#define GRID (NVEC / NPB)       // 512
#define KT (K_EMB / 16)         // 32 k-tiles

typedef __attribute__((ext_vector_type(8))) short bf16x8;
typedef __attribute__((ext_vector_type(4))) float f32x4;

// ws layout (bytes)
#define WS_E2   0
#define WS_EHI  4096
#define WS_ELO  (4096 + 65536)
#define WS_PART (4096 + 2 * 65536)

__device__ inline unsigned short f2bf(float f) {
    unsigned u = __float_as_uint(f);
    u += 0x7FFF + ((u >> 16) & 1);   // RNE
    return (unsigned short)(u >> 16);
}
__device__ inline float bf2f(unsigned short h) {
    return __uint_as_float(((unsigned)h) << 16);
}
__device__ inline bool lessidx(float s, int i, float t, int j) {
    return (s < t) || (s == t && i < j);
}

// ---- prep: e2[k]; frag-linear bf16 hi/lo of (-2*emb) ----
// frag layout: region r = kt*2 + s (s = K-step), lane l holds 8 bf16 =
// A[row = kt*16 + (l&15)][c = 32*s + (l>>4)*8 + j], stored at (r*64+l)*8 shorts.
__global__ __launch_bounds__(512) void vq_prep(const float* __restrict__ emb,
                                               float* __restrict__ e2,
                                               short* __restrict__ ehi,
                                               short* __restrict__ elo) {
    const int t = blockIdx.x * 512 + threadIdx.x;   // 0..4095
    const int l = t & 63;
    const int kt2 = t >> 6;                         // kt*2 + s
    const int row = (kt2 >> 1) * 16 + (l & 15);
    const int cb  = (kt2 & 1) * 32 + (l >> 4) * 8;
    const float* src = emb + row * C_DIM + cb;
    bf16x8 vh, vl;
#pragma unroll
    for (int j = 0; j < 8; ++j) {
        float v = -2.0f * src[j];
        unsigned short h = f2bf(v);
        float hf = bf2f(h);
        unsigned short q = f2bf(v - hf);
        vh[j] = (short)h;
        vl[j] = (short)q;
    }
    *(bf16x8*)(ehi + (size_t)t * 8) = vh;
    *(bf16x8*)(elo + (size_t)t * 8) = vl;

    if (t < K_EMB) {
        const float* r = emb + t * C_DIM;
        float s = 0.f;
#pragma unroll
        for (int c = 0; c < C_DIM; ++c) s += r[c] * r[c];
        e2[t] = s;
    }
}

__global__ __launch_bounds__(BLK) void vq_main(
    const float* __restrict__ x,
    const float* __restrict__ emb,
    const float* __restrict__ e2g,
    const short* __restrict__ ehi_g,
    const short* __restrict__ elo_g,
    float* __restrict__ out,
    double* __restrict__ partials)
{
    __shared__ __align__(16) short s_hi[K_EMB * C_DIM];  // 64 KB, frag-linear
    __shared__ __align__(16) short s_lo[K_EMB * C_DIM];  // 64 KB
    __shared__ __align__(16) float s_e2[K_EMB];          // 2 KB
    __shared__ int    s_idx[NPB];                        // 1 KB
    __shared__ double s_wsum[8];

    const int tid = threadIdx.x;

    // ---- stage tables into LDS (linear copy, coalesced) ----
    {
        const float4* srch = (const float4*)ehi_g;
        const float4* srcl = (const float4*)elo_g;
        float4* dsth = (float4*)s_hi;
        float4* dstl = (float4*)s_lo;
#pragma unroll
        for (int i = 0; i < 8; ++i) dsth[tid + i * BLK] = srch[tid + i * BLK];
#pragma unroll
        for (int i = 0; i < 8; ++i) dstl[tid + i * BLK] = srcl[tid + i * BLK];
        if (tid < K_EMB) s_e2[tid] = e2g[tid];
    }
    __syncthreads();

    const int lane = tid & 63;
    const int wid  = tid >> 6;
    const int lr   = lane & 15;
    const int lh   = lane >> 4;
    const int nbase = blockIdx.x * NPB + wid * 32;

    // ---- x -> B-fragments (hi/lo), x2 partials ----
    // B-frag: lane l holds B[c = 32*s + (l>>4)*8 + j][n = base + (l&15)]
    bf16x8 xh[2][2], xl[2][2];   // [nt][s]
    float x2p[2] = {0.f, 0.f};
#pragma unroll
    for (int nt = 0; nt < 2; ++nt) {
        const int n = nbase + nt * 16 + lr;
        const float* xp = x + (size_t)n * C_DIM;
#pragma unroll
        for (int s = 0; s < 2; ++s) {
            const float* p = xp + s * 32 + lh * 8;
            float4 a = *(const float4*)(p);
            float4 b = *(const float4*)(p + 4);
            float vv[8] = {a.x, a.y, a.z, a.w, b.x, b.y, b.z, b.w};
#pragma unroll
            for (int j = 0; j < 8; ++j) {
                float v = vv[j];
                x2p[nt] += v * v;
                unsigned short h = f2bf(v);
                float hf = bf2f(h);
                unsigned short q = f2bf(v - hf);
                xh[nt][s][j] = (short)h;
                xl[nt][s][j] = (short)q;
            }
        }
    }

    // ---- k-loop: 32 tiles of 16 embeddings ----
    float best1[2] = {1e30f, 1e30f}, best2[2] = {1e30f, 1e30f};
    int bi1[2] = {0, 0}, bi2[2] = {0, 0};

#pragma unroll 2
    for (int kt = 0; kt < KT; ++kt) {
        const bf16x8* hp = (const bf16x8*)s_hi + kt * 128 + lane;
        const bf16x8* lp = (const bf16x8*)s_lo + kt * 128 + lane;
        bf16x8 ah0 = hp[0], ah1 = hp[64];
        bf16x8 al0 = lp[0], al1 = lp[64];
        float4 ev = *(const float4*)(s_e2 + kt * 16 + lh * 4);
        f32x4 acc0 = {ev.x, ev.y, ev.z, ev.w};
        f32x4 acc1 = acc0;

        acc0 = __builtin_amdgcn_mfma_f32_16x16x32_bf16(ah0, xh[0][0], acc0, 0, 0, 0);
        acc1 = __builtin_amdgcn_mfma_f32_16x16x32_bf16(ah0, xh[1][0], acc1, 0, 0, 0);
        acc0 = __builtin_amdgcn_mfma_f32_16x16x32_bf16(ah1, xh[0][1], acc0, 0, 0, 0);
        acc1 = __builtin_amdgcn_mfma_f32_16x16x32_bf16(ah1, xh[1][1], acc1, 0, 0, 0);
        acc0 = __builtin_amdgcn_mfma_f32_16x16x32_bf16(al0, xh[0][0], acc0, 0, 0, 0);
        acc1 = __builtin_amdgcn_mfma_f32_16x16x32_bf16(al0, xh[1][0], acc1, 0, 0, 0);
        acc0 = __builtin_amdgcn_mfma_f32_16x16x32_bf16(al1, xh[0][1], acc0, 0, 0, 0);
        acc1 = __builtin_amdgcn_mfma_f32_16x16x32_bf16(al1, xh[1][1], acc1, 0, 0, 0);
        acc0 = __builtin_amdgcn_mfma_f32_16x16x32_bf16(ah0, xl[0][0], acc0, 0, 0, 0);
        acc1 = __builtin_amdgcn_mfma_f32_16x16x32_bf16(ah0, xl[1][0], acc1, 0, 0, 0);
        acc0 = __builtin_amdgcn_mfma_f32_16x16x32_bf16(ah1, xl[0][1], acc0, 0, 0, 0);
        acc1 = __builtin_amdgcn_mfma_f32_16x16x32_bf16(ah1, xl[1][1], acc1, 0, 0, 0);

        const int kb = kt * 16 + lh * 4;
#pragma unroll
        for (int r = 0; r < 4; ++r) {
            float s0 = acc0[r];
            if (s0 < best2[0]) {
                if (s0 < best1[0]) { best2[0] = best1[0]; bi2[0] = bi1[0];
                                     best1[0] = s0; bi1[0] = kb + r; }
                else               { best2[0] = s0; bi2[0] = kb + r; }
            }
            float s1 = acc1[r];
            if (s1 < best2[1]) {
                if (s1 < best1[1]) { best2[1] = best1[1]; bi2[1] = bi1[1];
                                     best1[1] = s1; bi1[1] = kb + r; }
                else               { best2[1] = s1; bi2[1] = kb + r; }
            }
        }
    }

    // ---- cross-lane merge (groups lh=0..3), refine, stash ----
    double dsum = 0.0;
#pragma unroll
    for (int nt = 0; nt < 2; ++nt) {
        float b1 = best1[nt], b2 = best2[nt];
        int i1 = bi1[nt], i2 = bi2[nt];
        float xx = x2p[nt];
#pragma unroll
        for (int off = 16; off <= 32; off <<= 1) {
            float ob1 = __shfl_xor(b1, off, 64);
            int   oi1 = __shfl_xor(i1, off, 64);
            float ob2 = __shfl_xor(b2, off, 64);
            int   oi2 = __shfl_xor(i2, off, 64);
            float oxx = __shfl_xor(xx, off, 64);
            xx += oxx;
            bool to = lessidx(ob1, oi1, b1, i1);
            float w1 = to ? ob1 : b1;  int wi1 = to ? oi1 : i1;
            float l1 = to ? b1 : ob1;  int li1 = to ? i1 : oi1;
            float c2 = to ? ob2 : b2;  int ci2 = to ? oi2 : i2;
            bool t2 = lessidx(l1, li1, c2, ci2);
            b1 = w1; i1 = wi1;
            b2 = t2 ? l1 : c2; i2 = t2 ? li1 : ci2;
        }

        if (lane < 16) {
            double md;
            int bw = i1;
            if (b2 - b1 < 1e-2f) {
                const int n = nbase + nt * 16 + lane;
                const float4* xq = (const float4*)(x + (size_t)n * C_DIM);
                const float4* p1 = (const float4*)(emb + (size_t)i1 * C_DIM);
                const float4* p2 = (const float4*)(emb + (size_t)i2 * C_DIM);
                double s1 = 0.0, s2 = 0.0;
#pragma unroll
                for (int i = 0; i < 16; ++i) {
                    float4 xv = xq[i]; float4 a = p1[i]; float4 bq = p2[i];
                    double d;
                    d = (double)xv.x - (double)a.x;  s1 = fma(d, d, s1);
                    d = (double)xv.y - (double)a.y;  s1 = fma(d, d, s1);
                    d = (double)xv.z - (double)a.z;  s1 = fma(d, d, s1);
                    d = (double)xv.w - (double)a.w;  s1 = fma(d, d, s1);
                    d = (double)xv.x - (double)bq.x; s2 = fma(d, d, s2);
                    d = (double)xv.y - (double)bq.y; s2 = fma(d, d, s2);
                    d = (double)xv.z - (double)bq.z; s2 = fma(d, d, s2);
                    d = (double)xv.w - (double)bq.w; s2 = fma(d, d, s2);
                }
                if (s2 < s1 || (s1 == s2 && i2 < i1)) { bw = i2; md = s2; }
                else                                   { md = s1; }
            } else {
                md = (double)xx + (double)b1;
            }
            s_idx[wid * 32 + nt * 16 + lane] = bw;
            dsum += md;
        }
    }

    // ---- loss partial: sum over lanes 0..15 (each holds 2 vectors) ----
    if (lane < 16) {
#pragma unroll
        for (int off = 1; off <= 8; off <<= 1) dsum += __shfl_xor(dsum, off, 64);
    }
    if (lane == 0) s_wsum[wid] = dsum;
    __syncthreads();

    // ---- output gather: 256 rows x 16 float4 chunks = 4096 tasks ----
#pragma unroll
    for (int it = 0; it < 8; ++it) {
        int task = it * BLK + tid;
        int row = task >> 4, c4 = task & 15;
        int bidx = s_idx[row];
        float4 v = ((const float4*)emb)[bidx * 16 + c4];
        ((float4*)out)[((size_t)blockIdx.x * NPB + row) * 16 + c4] = v;
    }

    if (tid == 0) {
        double t = 0.0;
#pragma unroll
        for (int i = 0; i < 8; ++i) t += s_wsum[i];
        partials[blockIdx.x] = t;
    }
}

__global__ __launch_bounds__(512) void vq_finalize(const double* __restrict__ partials,
                                                   float* __restrict__ out) {
    double v = partials[threadIdx.x];
#pragma unroll
    for (int off = 32; off; off >>= 1) v += __shfl_down(v, off, 64);
    __shared__ double ls[8];
    const int lane = threadIdx.x & 63;
    const int wid  = threadIdx.x >> 6;
    if (lane == 0) ls[wid] = v;
    __syncthreads();
    if (threadIdx.x == 0) {
        double t = 0.0;
#pragma unroll
        for (int i = 0; i < 8; ++i) t += ls[i];
        double mean = t / (double)((size_t)NVEC * C_DIM);
        out[(size_t)NVEC * C_DIM] = (float)(1.25 * mean);
    }
}

extern "C" void kernel_launch(void* const* d_in, const int* in_sizes, int n_in,
                              void* d_out, int out_size, void* d_ws, size_t ws_size,
                              hipStream_t stream) {
    const float* x   = (const float*)d_in[0];
    const float* emb = (const float*)d_in[1];
    float* out = (float*)d_out;

    float*  e2       = (float*)((char*)d_ws + WS_E2);
    short*  ehi      = (short*)((char*)d_ws + WS_EHI);
    short*  elo      = (short*)((char*)d_ws + WS_ELO);
    double* partials = (double*)((char*)d_ws + WS_PART);

    vq_prep<<<8, 512, 0, stream>>>(emb, e2, ehi, elo);
    vq_main<<<GRID, BLK, 0, stream>>>(x, emb, e2, ehi, elo, out, partials);
    vq_finalize<<<1, 512, 0, stream>>>(partials, out);
}

// Round 3
// 48.821 us; speedup vs baseline: 5.0388x; 1.3863x over previous
//
#include <hip/hip_runtime.h>

// VectorQuantization: x (32,64,64,64) f32, embedding (512,64) f32
// out = [quantized_ste (8388608 f32)] ++ [loss (1 f32)]
//
// score[k,n] = e2[k] - 2*dot(e_k, x_n); argmin_k; gather; loss=1.25*mean dist.
// bf16 3-pass MFMA (hi*hi + lo*hi + hi*lo), top-2 + fp64 refine (gap<1.2e-2).
// Round 3: BLK=1024 (16 waves/CU), packed-score branch-free top-2 argmin.

#define C_DIM 64
#define K_EMB 512
#define NVEC (32 * 64 * 64)     // 131072
#define BLK 1024                // 16 waves
#define NPB 512                 // vectors per block (16 waves x 32)
#define GRID (NVEC / NPB)       // 256 = 1 block/CU
#define KT (K_EMB / 16)         // 32 k-tiles

typedef __attribute__((ext_vector_type(8))) short bf16x8;
typedef __attribute__((ext_vector_type(4))) float f32x4;

// ws layout (bytes)
#define WS_E2   0
#define WS_EHI  4096
#define WS_ELO  (4096 + 65536)
#define WS_PART (4096 + 2 * 65536)

__device__ inline unsigned short f2bf(float f) {
    unsigned u = __float_as_uint(f);
    u += 0x7FFF + ((u >> 16) & 1);   // RNE
    return (unsigned short)(u >> 16);
}
__device__ inline float bf2f(unsigned short h) {
    return __uint_as_float(((unsigned)h) << 16);
}
__device__ inline bool lessidx(float s, int i, float t, int j) {
    return (s < t) || (s == t && i < j);
}

// ---- prep: e2[k]; frag-linear bf16 hi/lo of (-2*emb) ----
// frag layout: region r = kt*2 + s (s = K-step), lane l holds 8 bf16 =
// A[row = kt*16 + (l&15)][c = 32*s + (l>>4)*8 + j], stored at (r*64+l)*8 shorts.
__global__ __launch_bounds__(512) void vq_prep(const float* __restrict__ emb,
                                               float* __restrict__ e2,
                                               short* __restrict__ ehi,
                                               short* __restrict__ elo) {
    const int t = blockIdx.x * 512 + threadIdx.x;   // 0..4095
    const int l = t & 63;
    const int kt2 = t >> 6;                         // kt*2 + s
    const int row = (kt2 >> 1) * 16 + (l & 15);
    const int cb  = (kt2 & 1) * 32 + (l >> 4) * 8;
    const float* src = emb + row * C_DIM + cb;
    bf16x8 vh, vl;
#pragma unroll
    for (int j = 0; j < 8; ++j) {
        float v = -2.0f * src[j];
        unsigned short h = f2bf(v);
        float hf = bf2f(h);
        unsigned short q = f2bf(v - hf);
        vh[j] = (short)h;
        vl[j] = (short)q;
    }
    *(bf16x8*)(ehi + (size_t)t * 8) = vh;
    *(bf16x8*)(elo + (size_t)t * 8) = vl;

    if (t < K_EMB) {
        const float* r = emb + t * C_DIM;
        float s = 0.f;
#pragma unroll
        for (int c = 0; c < C_DIM; ++c) s += r[c] * r[c];
        e2[t] = s;
    }
}

__global__ __launch_bounds__(BLK) void vq_main(
    const float* __restrict__ x,
    const float* __restrict__ emb,
    const float* __restrict__ e2g,
    const short* __restrict__ ehi_g,
    const short* __restrict__ elo_g,
    float* __restrict__ out,
    double* __restrict__ partials)
{
    __shared__ __align__(16) short s_hi[K_EMB * C_DIM];  // 64 KB, frag-linear
    __shared__ __align__(16) short s_lo[K_EMB * C_DIM];  // 64 KB
    __shared__ __align__(16) float s_e2[K_EMB];          // 2 KB
    __shared__ int    s_idx[NPB];                        // 2 KB
    __shared__ double s_wsum[BLK / 64];

    const int tid = threadIdx.x;

    // ---- stage tables into LDS (linear copy, coalesced) ----
    {
        const float4* srch = (const float4*)ehi_g;
        const float4* srcl = (const float4*)elo_g;
        float4* dsth = (float4*)s_hi;
        float4* dstl = (float4*)s_lo;
#pragma unroll
        for (int i = 0; i < 4; ++i) dsth[tid + i * BLK] = srch[tid + i * BLK];
#pragma unroll
        for (int i = 0; i < 4; ++i) dstl[tid + i * BLK] = srcl[tid + i * BLK];
        if (tid < K_EMB) s_e2[tid] = e2g[tid];
    }
    __syncthreads();

    const int lane = tid & 63;
    const int wid  = tid >> 6;
    const int lr   = lane & 15;
    const int lh   = lane >> 4;
    const int nbase = blockIdx.x * NPB + wid * 32;

    // ---- x -> B-fragments (hi/lo), x2 partials ----
    // B-frag: lane l holds B[c = 32*s + (l>>4)*8 + j][n = base + (l&15)]
    bf16x8 xh[2][2], xl[2][2];   // [nt][s]
    float x2p[2] = {0.f, 0.f};
#pragma unroll
    for (int nt = 0; nt < 2; ++nt) {
        const int n = nbase + nt * 16 + lr;
        const float* xp = x + (size_t)n * C_DIM;
#pragma unroll
        for (int s = 0; s < 2; ++s) {
            const float* p = xp + s * 32 + lh * 8;
            float4 a = *(const float4*)(p);
            float4 b = *(const float4*)(p + 4);
            float vv[8] = {a.x, a.y, a.z, a.w, b.x, b.y, b.z, b.w};
#pragma unroll
            for (int j = 0; j < 8; ++j) {
                float v = vv[j];
                x2p[nt] += v * v;
                unsigned short h = f2bf(v);
                float hf = bf2f(h);
                unsigned short q = f2bf(v - hf);
                xh[nt][s][j] = (short)h;
                xl[nt][s][j] = (short)q;
            }
        }
    }

    // ---- k-loop: 32 tiles of 16 embeddings; packed branch-free top-2 ----
    // packed value = (round_to_7bits(score) & ~127) | (kt*4 + r)   [lane-local idx]
    float pb1[2] = {1e30f, 1e30f}, pb2[2] = {1e30f, 1e30f};

#pragma unroll 2
    for (int kt = 0; kt < KT; ++kt) {
        const bf16x8* hp = (const bf16x8*)s_hi + kt * 128 + lane;
        const bf16x8* lp = (const bf16x8*)s_lo + kt * 128 + lane;
        bf16x8 ah0 = hp[0], ah1 = hp[64];
        bf16x8 al0 = lp[0], al1 = lp[64];
        float4 ev = *(const float4*)(s_e2 + kt * 16 + lh * 4);
        f32x4 acc0 = {ev.x, ev.y, ev.z, ev.w};
        f32x4 acc1 = acc0;

        acc0 = __builtin_amdgcn_mfma_f32_16x16x32_bf16(ah0, xh[0][0], acc0, 0, 0, 0);
        acc1 = __builtin_amdgcn_mfma_f32_16x16x32_bf16(ah0, xh[1][0], acc1, 0, 0, 0);
        acc0 = __builtin_amdgcn_mfma_f32_16x16x32_bf16(ah1, xh[0][1], acc0, 0, 0, 0);
        acc1 = __builtin_amdgcn_mfma_f32_16x16x32_bf16(ah1, xh[1][1], acc1, 0, 0, 0);
        acc0 = __builtin_amdgcn_mfma_f32_16x16x32_bf16(al0, xh[0][0], acc0, 0, 0, 0);
        acc1 = __builtin_amdgcn_mfma_f32_16x16x32_bf16(al0, xh[1][0], acc1, 0, 0, 0);
        acc0 = __builtin_amdgcn_mfma_f32_16x16x32_bf16(al1, xh[0][1], acc0, 0, 0, 0);
        acc1 = __builtin_amdgcn_mfma_f32_16x16x32_bf16(al1, xh[1][1], acc1, 0, 0, 0);
        acc0 = __builtin_amdgcn_mfma_f32_16x16x32_bf16(ah0, xl[0][0], acc0, 0, 0, 0);
        acc1 = __builtin_amdgcn_mfma_f32_16x16x32_bf16(ah0, xl[1][0], acc1, 0, 0, 0);
        acc0 = __builtin_amdgcn_mfma_f32_16x16x32_bf16(ah1, xl[0][1], acc0, 0, 0, 0);
        acc1 = __builtin_amdgcn_mfma_f32_16x16x32_bf16(ah1, xl[1][1], acc1, 0, 0, 0);

        const unsigned kb4 = (unsigned)(kt * 4);
        // nt = 0
        {
            unsigned q0 = ((__float_as_uint(acc0[0]) + 64u) & 0xFFFFFF80u) | (kb4 + 0);
            unsigned q1 = ((__float_as_uint(acc0[1]) + 64u) & 0xFFFFFF80u) | (kb4 + 1);
            unsigned q2 = ((__float_as_uint(acc0[2]) + 64u) & 0xFFFFFF80u) | (kb4 + 2);
            unsigned q3 = ((__float_as_uint(acc0[3]) + 64u) & 0xFFFFFF80u) | (kb4 + 3);
            float f0 = __uint_as_float(q0), f1 = __uint_as_float(q1);
            float f2 = __uint_as_float(q2), f3 = __uint_as_float(q3);
            float a = fminf(f0, f1), b = fmaxf(f0, f1);
            pb2[0] = fminf(fminf(pb2[0], fmaxf(pb1[0], a)), b);
            pb1[0] = fminf(pb1[0], a);
            a = fminf(f2, f3); b = fmaxf(f2, f3);
            pb2[0] = fminf(fminf(pb2[0], fmaxf(pb1[0], a)), b);
            pb1[0] = fminf(pb1[0], a);
        }
        // nt = 1
        {
            unsigned q0 = ((__float_as_uint(acc1[0]) + 64u) & 0xFFFFFF80u) | (kb4 + 0);
            unsigned q1 = ((__float_as_uint(acc1[1]) + 64u) & 0xFFFFFF80u) | (kb4 + 1);
            unsigned q2 = ((__float_as_uint(acc1[2]) + 64u) & 0xFFFFFF80u) | (kb4 + 2);
            unsigned q3 = ((__float_as_uint(acc1[3]) + 64u) & 0xFFFFFF80u) | (kb4 + 3);
            float f0 = __uint_as_float(q0), f1 = __uint_as_float(q1);
            float f2 = __uint_as_float(q2), f3 = __uint_as_float(q3);
            float a = fminf(f0, f1), b = fmaxf(f0, f1);
            pb2[1] = fminf(fminf(pb2[1], fmaxf(pb1[1], a)), b);
            pb1[1] = fminf(pb1[1], a);
            a = fminf(f2, f3); b = fmaxf(f2, f3);
            pb2[1] = fminf(fminf(pb2[1], fmaxf(pb1[1], a)), b);
            pb1[1] = fminf(pb1[1], a);
        }
    }

    // ---- unpack, cross-lane merge (lh groups), refine, stash ----
    double dsum = 0.0;
#pragma unroll
    for (int nt = 0; nt < 2; ++nt) {
        unsigned u1 = __float_as_uint(pb1[nt]);
        unsigned u2 = __float_as_uint(pb2[nt]);
        int loc1 = u1 & 127, loc2 = u2 & 127;
        float b1 = __uint_as_float(u1 & 0xFFFFFF80u);
        float b2 = __uint_as_float(u2 & 0xFFFFFF80u);
        int i1 = ((loc1 >> 2) << 4) + lh * 4 + (loc1 & 3);
        int i2 = ((loc2 >> 2) << 4) + lh * 4 + (loc2 & 3);
        float xx = x2p[nt];
#pragma unroll
        for (int off = 16; off <= 32; off <<= 1) {
            float ob1 = __shfl_xor(b1, off, 64);
            int   oi1 = __shfl_xor(i1, off, 64);
            float ob2 = __shfl_xor(b2, off, 64);
            int   oi2 = __shfl_xor(i2, off, 64);
            float oxx = __shfl_xor(xx, off, 64);
            xx += oxx;
            bool to = lessidx(ob1, oi1, b1, i1);
            float w1 = to ? ob1 : b1;  int wi1 = to ? oi1 : i1;
            float l1 = to ? b1 : ob1;  int li1 = to ? i1 : oi1;
            float c2 = to ? ob2 : b2;  int ci2 = to ? oi2 : i2;
            bool t2 = lessidx(l1, li1, c2, ci2);
            b1 = w1; i1 = wi1;
            b2 = t2 ? l1 : c2; i2 = t2 ? li1 : ci2;
        }

        if (lane < 16) {
            double md;
            int bw = i1;
            if (b2 - b1 < 1.2e-2f) {
                const int n = nbase + nt * 16 + lane;
                const float4* xq = (const float4*)(x + (size_t)n * C_DIM);
                const float4* p1 = (const float4*)(emb + (size_t)i1 * C_DIM);
                const float4* p2 = (const float4*)(emb + (size_t)i2 * C_DIM);
                double s1 = 0.0, s2 = 0.0;
#pragma unroll
                for (int i = 0; i < 16; ++i) {
                    float4 xv = xq[i]; float4 a = p1[i]; float4 bq = p2[i];
                    double d;
                    d = (double)xv.x - (double)a.x;  s1 = fma(d, d, s1);
                    d = (double)xv.y - (double)a.y;  s1 = fma(d, d, s1);
                    d = (double)xv.z - (double)a.z;  s1 = fma(d, d, s1);
                    d = (double)xv.w - (double)a.w;  s1 = fma(d, d, s1);
                    d = (double)xv.x - (double)bq.x; s2 = fma(d, d, s2);
                    d = (double)xv.y - (double)bq.y; s2 = fma(d, d, s2);
                    d = (double)xv.z - (double)bq.z; s2 = fma(d, d, s2);
                    d = (double)xv.w - (double)bq.w; s2 = fma(d, d, s2);
                }
                if (s2 < s1 || (s1 == s2 && i2 < i1)) { bw = i2; md = s2; }
                else                                   { md = s1; }
            } else {
                md = (double)xx + (double)b1;
            }
            s_idx[wid * 32 + nt * 16 + lane] = bw;
            dsum += md;
        }
    }

    // ---- loss partial: sum over lanes 0..15 (each holds 2 vectors) ----
    if (lane < 16) {
#pragma unroll
        for (int off = 1; off <= 8; off <<= 1) dsum += __shfl_xor(dsum, off, 64);
    }
    if (lane == 0) s_wsum[wid] = dsum;
    __syncthreads();

    // ---- output gather: 512 rows x 16 float4 chunks = 8192 tasks ----
#pragma unroll
    for (int it = 0; it < 8; ++it) {
        int task = it * BLK + tid;
        int row = task >> 4, c4 = task & 15;
        int bidx = s_idx[row];
        float4 v = ((const float4*)emb)[bidx * 16 + c4];
        ((float4*)out)[((size_t)blockIdx.x * NPB + row) * 16 + c4] = v;
    }

    if (tid == 0) {
        double t = 0.0;
#pragma unroll
        for (int i = 0; i < BLK / 64; ++i) t += s_wsum[i];
        partials[blockIdx.x] = t;
    }
}

__global__ __launch_bounds__(256) void vq_finalize(const double* __restrict__ partials,
                                                   float* __restrict__ out) {
    double v = partials[threadIdx.x];   // 256 partials
#pragma unroll
    for (int off = 32; off; off >>= 1) v += __shfl_down(v, off, 64);
    __shared__ double ls[4];
    const int lane = threadIdx.x & 63;
    const int wid  = threadIdx.x >> 6;
    if (lane == 0) ls[wid] = v;
    __syncthreads();
    if (threadIdx.x == 0) {
        double t = ls[0] + ls[1] + ls[2] + ls[3];
        double mean = t / (double)((size_t)NVEC * C_DIM);
        out[(size_t)NVEC * C_DIM] = (float)(1.25 * mean);
    }
}

extern "C" void kernel_launch(void* const* d_in, const int* in_sizes, int n_in,
                              void* d_out, int out_size, void* d_ws, size_t ws_size,
                              hipStream_t stream) {
    const float* x   = (const float*)d_in[0];
    const float* emb = (const float*)d_in[1];
    float* out = (float*)d_out;

    float*  e2       = (float*)((char*)d_ws + WS_E2);
    short*  ehi      = (short*)((char*)d_ws + WS_EHI);
    short*  elo      = (short*)((char*)d_ws + WS_ELO);
    double* partials = (double*)((char*)d_ws + WS_PART);

    vq_prep<<<8, 512, 0, stream>>>(emb, e2, ehi, elo);
    vq_main<<<GRID, BLK, 0, stream>>>(x, emb, e2, ehi, elo, out, partials);
    vq_finalize<<<1, 256, 0, stream>>>(partials, out);
}